// Round 6
// baseline (71.208 us; speedup 1.0000x reference)
//
#include <hip/hip_runtime.h>
#include <hip/hip_bf16.h>

// ---------------------------------------------------------------------------
// Adapter: LayerNorm(2048) -> down(64) -> ReLU -> up(2048), 16384 tokens fp32.
// LN folded into down-proj (x read once):
//   down[n] = rstd*( dot(wg[n],x) - mu*s[n] ) + c[n],  wg = bf16(w_down*gamma)
// R6 = R5 with M=32 tokens/block (512 blocks x 4 waves):
//  - each wave: 16 n over full K, TWO M-fragments sharing each B-fragment
//    -> weight L2 traffic and barriers PER TOKEN halved
//  - f32->bf16 via __float2bfloat16 (compiler emits v_cvt_pk_bf16_f32)
//  - same 1-barrier/chunk dbuf protocol, reg-staged x 3 chunks deep
// ---------------------------------------------------------------------------

typedef __attribute__((ext_vector_type(8))) short short8;   // 8 x bf16
typedef __attribute__((ext_vector_type(4))) float f32x4;

#define D_MODEL 2048
#define BNECK   64
#define EPS     1e-5f
#define NCHUNK  32          // chunks of K=64 (256B per row)

__device__ inline short f2bf(float f) {                     // prep only
    unsigned int u = __builtin_bit_cast(unsigned int, f);
    unsigned int r = (u + 0x7fffu + ((u >> 16) & 1u)) >> 16; // RNE
    return (short)r;
}
__device__ inline float bf2f(short s) {
    unsigned int u = ((unsigned int)(unsigned short)s) << 16;
    return __builtin_bit_cast(float, u);
}
__device__ inline short hbf(float f) {                      // HW RNE cvt
    __hip_bfloat16 h = __float2bfloat16(f);
    return __builtin_bit_cast(short, h);
}
__device__ inline short8 cvt8(const f32x4& a, const f32x4& b) {
    short8 o;
    o[0] = hbf(a.x); o[1] = hbf(a.y); o[2] = hbf(a.z); o[3] = hbf(a.w);
    o[4] = hbf(b.x); o[5] = hbf(b.y); o[6] = hbf(b.z); o[7] = hbf(b.w);
    return o;
}

// ---------------------------------------------------------------------------
// Prep. wg_perm slot = (n>>4)*64 + (k>>5): per-wave contiguous 64KB stream.
// Within slot: lane l = ((k>>3)&3)*16 + (n&15), elem e = k&7.
// wup_perm: slot (b16*2+h): lane l -> (d=b16*16+(l&15), kn=h*32+(l>>4)*8+e).
// s[n] = sum_k bf16(wg), c[n] = w_down[n,:].beta + b_down[n].
// ---------------------------------------------------------------------------
__global__ __launch_bounds__(256) void prep_kernel(
    const float* __restrict__ w_down, const float* __restrict__ gamma,
    const float* __restrict__ beta,   const float* __restrict__ b_down,
    const float* __restrict__ w_up,
    short* __restrict__ wg_perm, short* __restrict__ wup_perm,
    float* __restrict__ s_out, float* __restrict__ c_out)
{
    __shared__ float rs[4], rc[4];
    int b = blockIdx.x;
    if (b < BNECK) {
        int n = b, nf = n >> 4;
        float ps = 0.f, pc = 0.f;
        for (int d = threadIdx.x; d < D_MODEL; d += 256) {
            float wv = w_down[n * D_MODEL + d];
            short h  = f2bf(wv * gamma[d]);
            int t = d >> 5, kg = (d >> 3) & 3, e = d & 7;
            int l = kg * 16 + (n & 15);
            wg_perm[(size_t)((nf * 64 + t) * 64 + l) * 8 + e] = h;
            ps += bf2f(h);
            pc  = fmaf(wv, beta[d], pc);
        }
        for (int o = 32; o > 0; o >>= 1) {
            ps += __shfl_down(ps, o, 64);
            pc += __shfl_down(pc, o, 64);
        }
        int wid = threadIdx.x >> 6, lane = threadIdx.x & 63;
        if (lane == 0) { rs[wid] = ps; rc[wid] = pc; }
        __syncthreads();
        if (threadIdx.x == 0) {
            s_out[n] = rs[0] + rs[1] + rs[2] + rs[3];
            c_out[n] = rc[0] + rc[1] + rc[2] + rc[3] + b_down[n];
        }
    } else {
        for (int j = (b - BNECK) * 256 + threadIdx.x; j < D_MODEL * BNECK;
             j += 64 * 256) {
            int d = j >> 6, kn = j & 63;
            int b16 = d >> 4, h2 = kn >> 5, e = kn & 7;
            int l = ((kn >> 3) & 3) * 16 + (d & 15);
            wup_perm[(size_t)((b16 * 2 + h2) * 64 + l) * 8 + e] = f2bf(w_up[j]);
        }
    }
}

// ---------------------------------------------------------------------------
// Main kernel. 512 blocks x 256 threads; block owns 32 tokens; waves n-split.
// ---------------------------------------------------------------------------
__global__ __launch_bounds__(256, 4) void adapter_kernel(
    const float* __restrict__ x,    const float* __restrict__ b_up,
    const short* __restrict__ wg_perm, const short* __restrict__ wup_perm,
    const float* __restrict__ s_v,  const float* __restrict__ c_v,
    float* __restrict__ out)
{
    __shared__ __align__(16) char xbuf[2][8192];   // dbuf: 32 rows x 256B
    __shared__ __align__(16) char tilebuf[4096];   // 32x64 bf16, swizzled
    __shared__ float stats2[32][2];                // per-token (mu, rstd)

    const int wid  = threadIdx.x >> 6;
    const int lane = threadIdx.x & 63;
    const int r    = lane & 15;          // frag row/col index
    const int g    = lane >> 4;          // k-group
    const int row0 = blockIdx.x * 32;
    const int swz  = (r & 7) << 4;

    // ---- cooperative staging: wave wid owns rows [wid*8, wid*8+8) ---------
    // lane stages 32B of row sr at byte col (r&7)*32 within the 256B chunk.
    const int sr  = wid * 8 + g * 2 + (r >> 3);
    const int scb = (r & 7) * 32;
    const char* xsrc = (const char*)x
        + ((size_t)(row0 + sr) * D_MODEL) * 4 + scb;
    const int swr = (sr & 7) << 4;
    char* const swdst0 = &xbuf[0][0] + sr * 256 + ( scb       ^ swr);
    char* const swdst1 = &xbuf[0][0] + sr * 256 + ((scb + 16) ^ swr);

    const short* wbase = wg_perm + (size_t)(wid * 64) * 512 + lane * 8;

    f32x4  xr[4][2];         // register-staged x chunks (3 in flight, 32B ea)
    short8 wb[2][2];         // weight frags, 1 chunk ahead
    f32x4  acc0 = (f32x4){0.f, 0.f, 0.f, 0.f};
    f32x4  acc1 = (f32x4){0.f, 0.f, 0.f, 0.f};
    float  ssum = 0.f, ssq = 0.f;

    auto LDX = [&](int c, f32x4* o) {
        o[0] = *(const f32x4*)(xsrc + c * 256);
        o[1] = *(const f32x4*)(xsrc + c * 256 + 16);
    };
    auto LDW = [&](int c, short8* w) {
        w[0] = *(const short8*)(wbase + (size_t)(c * 2 + 0) * 512);
        w[1] = *(const short8*)(wbase + (size_t)(c * 2 + 1) * 512);
    };
    auto STATS_WRITE = [&](int c, const f32x4* v) {   // stats + publish to LDS
#pragma unroll
        for (int h = 0; h < 2; ++h) {
            ssum += (v[h].x + v[h].y) + (v[h].z + v[h].w);
            ssq = fmaf(v[h].x, v[h].x, ssq); ssq = fmaf(v[h].y, v[h].y, ssq);
            ssq = fmaf(v[h].z, v[h].z, ssq); ssq = fmaf(v[h].w, v[h].w, ssq);
        }
        *(f32x4*)(swdst0 + (size_t)(c & 1) * 8192) = v[0];
        *(f32x4*)(swdst1 + (size_t)(c & 1) * 8192) = v[1];
    };

    // prologue: 3 chunks of x in flight, weights 1 chunk ahead
    LDX(0, xr[0]); LDX(1, xr[1]); LDX(2, xr[2]);
    LDW(0, wb[0]);
    STATS_WRITE(0, xr[0]);

#pragma unroll
    for (int c = 0; c < NCHUNK; ++c) {
        if (c + 3 < NCHUNK) LDX(c + 3, xr[(c + 3) & 3]);
        if (c + 1 < NCHUNK) LDW(c + 1, wb[(c + 1) & 1]);
        // publish writes of chunk c; certify reads of buf[(c+1)&1] finished
        asm volatile("s_waitcnt lgkmcnt(0)\n\ts_barrier" ::: "memory");
        if (c + 1 < NCHUNK) STATS_WRITE(c + 1, xr[(c + 1) & 3]);

        const char* bp = &xbuf[c & 1][0];
        const short8* w = wb[c & 1];
#pragma unroll
        for (int kb = 0; kb < 2; ++kb) {
            int cb = kb * 128 + g * 32;
            f32x4 xa0 = *(const f32x4*)(bp + r * 256        + ( cb       ^ swz));
            f32x4 xb0 = *(const f32x4*)(bp + r * 256        + ((cb + 16) ^ swz));
            f32x4 xa1 = *(const f32x4*)(bp + (16 + r) * 256 + ( cb       ^ swz));
            f32x4 xb1 = *(const f32x4*)(bp + (16 + r) * 256 + ((cb + 16) ^ swz));
            acc0 = __builtin_amdgcn_mfma_f32_16x16x32_bf16(cvt8(xa0, xb0), w[kb], acc0, 0, 0, 0);
            acc1 = __builtin_amdgcn_mfma_f32_16x16x32_bf16(cvt8(xa1, xb1), w[kb], acc1, 0, 0, 0);
        }
    }

    // ---- LN stats: 8 lanes (r&7) share row sr -> xor-reduce over bits 0..2
#pragma unroll
    for (int m = 1; m < 8; m <<= 1) {
        ssum += __shfl_xor(ssum, m, 64);
        ssq  += __shfl_xor(ssq , m, 64);
    }
    float mu   = ssum * (1.f / D_MODEL);
    float rstd = rsqrtf(ssq * (1.f / D_MODEL) - mu * mu + EPS);
    if ((r & 7) == 0) { stats2[sr][0] = mu; stats2[sr][1] = rstd; }
    __syncthreads();

    // ---- fix-up + ReLU: wave owns n = wid*16+r; tokens m = mb*16+g*4+reg --
    {
        int   n  = wid * 16 + r;
        float sn = s_v[n], cn = c_v[n];
#pragma unroll
        for (int mb = 0; mb < 2; ++mb) {
            const f32x4& a = mb ? acc1 : acc0;
#pragma unroll
            for (int reg = 0; reg < 4; ++reg) {
                int   m = mb * 16 + g * 4 + reg;
                float v = fmaf(stats2[m][1], a[reg] - stats2[m][0] * sn, cn);
                v = fmaxf(v, 0.f);
                *(short*)(tilebuf + ((m * 128 + n * 2) ^ ((m & 7) << 4))) = hbf(v);
            }
        }
    }
    __syncthreads();

    // ---- up-GEMM (A = w_up fragment-major, B = down^T), 2 token-blocks ----
    short8 bd[2][2];
#pragma unroll
    for (int tb = 0; tb < 2; ++tb) {
        int t = tb * 16 + r;
        bd[tb][0] = *(const short8*)(tilebuf + ((t * 128 +  0 + g * 16) ^ swz));
        bd[tb][1] = *(const short8*)(tilebuf + ((t * 128 + 64 + g * 16) ^ swz));
    }

    const short* wupl = wup_perm + lane * 8;
    float* outr0 = out + (size_t)(row0 + r) * D_MODEL;
    float* outr1 = out + (size_t)(row0 + 16 + r) * D_MODEL;

    short8 ua[2], ub[2];
    {
        int b16 = wid * 32;
        ua[0] = *(const short8*)(wupl + (size_t)(b16 * 2 + 0) * 512);
        ub[0] = *(const short8*)(wupl + (size_t)(b16 * 2 + 1) * 512);
    }
#pragma unroll
    for (int i = 0; i < 32; ++i) {
        int cur = i & 1;
        if (i < 31) {
            int b16 = wid * 32 + i + 1;
            ua[cur ^ 1] = *(const short8*)(wupl + (size_t)(b16 * 2 + 0) * 512);
            ub[cur ^ 1] = *(const short8*)(wupl + (size_t)(b16 * 2 + 1) * 512);
        }
        int dbase = (wid * 32 + i) * 16;
        f32x4 bu = *(const f32x4*)(b_up + dbase + g * 4);

        f32x4 o0 = (f32x4){0.f, 0.f, 0.f, 0.f};
        o0 = __builtin_amdgcn_mfma_f32_16x16x32_bf16(ua[cur], bd[0][0], o0, 0, 0, 0);
        o0 = __builtin_amdgcn_mfma_f32_16x16x32_bf16(ub[cur], bd[0][1], o0, 0, 0, 0);
        f32x4 o1 = (f32x4){0.f, 0.f, 0.f, 0.f};
        o1 = __builtin_amdgcn_mfma_f32_16x16x32_bf16(ua[cur], bd[1][0], o1, 0, 0, 0);
        o1 = __builtin_amdgcn_mfma_f32_16x16x32_bf16(ub[cur], bd[1][1], o1, 0, 0, 0);

        *(f32x4*)(outr0 + dbase + g * 4) = o0 + bu;
        *(f32x4*)(outr1 + dbase + g * 4) = o1 + bu;
    }
}

extern "C" void kernel_launch(void* const* d_in, const int* in_sizes, int n_in,
                              void* d_out, int out_size, void* d_ws, size_t ws_size,
                              hipStream_t stream) {
    const float* x      = (const float*)d_in[0];
    const float* gamma  = (const float*)d_in[1];
    const float* beta   = (const float*)d_in[2];
    const float* w_down = (const float*)d_in[3];
    const float* b_down = (const float*)d_in[4];
    const float* w_up   = (const float*)d_in[5];
    const float* b_up   = (const float*)d_in[6];
    float* out = (float*)d_out;

    char* ws = (char*)d_ws;
    short* wg_perm  = (short*)ws;                 // 256 KB
    short* wup_perm = (short*)(ws + 262144);      // 256 KB
    float* s_v  = (float*)(ws + 524288);          // 256 B
    float* c_v  = (float*)(ws + 524544);          // 256 B

    prep_kernel<<<128, 256, 0, stream>>>(w_down, gamma, beta, b_down, w_up,
                                         wg_perm, wup_perm, s_v, c_v);
    adapter_kernel<<<512, 256, 0, stream>>>(x, b_up, wg_perm, wup_perm,
                                            s_v, c_v, out);
}